// Round 2
// baseline (70.762 us; speedup 1.0000x reference)
//
#include <hip/hip_runtime.h>
#include <hip/hip_bf16.h>

// DivEncLayer: per (b,q): z = W1[q]^T x[b, q*8 .. +8) + b1;  h = BN(elu(z));  out = W2[q]^T h + b2
// B=32768, Q=128, S=8, H=32.  ALL tensors float32 (verified via npz sizes: x=134MB, out=16.8MB raw).
//
// BN folded into second dense: W2p = gamma*rsqrt(var+eps)*W2 ; b2p = b2 + sum((beta-mean*inv)*W2).
// Thread = (q, h-half of 16). W1 fragment (8x16 f32) kept in 128 VGPRs, amortized over 64 b-rows.
// Wave = 32 q x 2 h-halves; 32B x-load per (thread,b) (lane pairs share a cache line -> coalesced);
// shfl_xor(1) combines the two h-halves; software prefetch of next row's x hides HBM latency.

#define QN 128
#define SN 8
#define HN 32
#define XROW 1024            // Q*S elements per batch row
#define BN_EPS 1e-3f

__global__ __launch_bounds__(256, 2)
void divenc_main(const float* __restrict__ x,
                 const float* __restrict__ W1,
                 const float* __restrict__ b1,
                 const float* __restrict__ gamma_,
                 const float* __restrict__ beta_,
                 const float* __restrict__ mmean,
                 const float* __restrict__ mvar,
                 const float* __restrict__ W2,
                 const float* __restrict__ b2,
                 float* __restrict__ out,
                 int b_per_stripe, int Btot)
{
    const int lane = threadIdx.x & 63;
    const int wave = threadIdx.x >> 6;
    const int ql   = lane >> 1;        // 0..31
    const int hg   = lane & 1;         // 0..1  (h-half)
    const int q    = blockIdx.x * 32 + ql;
    const int h0   = hg * 16;

    // ---- one-time: BN fold into second dense (f32) ----
    float w2p[16];
    float bsum = 0.f;
    {
        const int base = q * HN + h0;
        #pragma unroll
        for (int k = 0; k < 16; ++k) {
            float g  = gamma_[base + k];
            float bt = beta_[base + k];
            float mn = mmean[base + k];
            float vr = mvar[base + k];
            float w2 = W2[base + k];
            float inv = g * rsqrtf(vr + BN_EPS);
            w2p[k] = inv * w2;
            bsum += (bt - mn * inv) * w2;
        }
    }
    bsum += __shfl_xor(bsum, 1);
    const float b2p = bsum + b2[q];

    // ---- one-time: W1 fragment (8 x 16) and b1 into registers ----
    float w1f[8][16];
    #pragma unroll
    for (int s = 0; s < 8; ++s) {
        const float* wp = W1 + (size_t)(q * SN + s) * HN + h0;
        #pragma unroll
        for (int k = 0; k < 16; ++k) w1f[s][k] = wp[k];
    }
    float b1f[16];
    {
        const float* bp = b1 + q * HN + h0;
        #pragma unroll
        for (int k = 0; k < 16; ++k) b1f[k] = bp[k];
    }

    // ---- main loop over batch rows ----
    const int stripe = blockIdx.y * 4 + wave;
    int b = stripe * b_per_stripe;
    int bend = b + b_per_stripe;
    if (bend > Btot) bend = Btot;
    if (b >= bend) return;

    const float* xp = x + (size_t)b * XROW + q * SN;
    float4 xv0 = *(const float4*)xp;
    float4 xv1 = *(const float4*)(xp + 4);

    for (; b < bend; ++b) {
        float4 xn0 = xv0, xn1 = xv1;
        if (b + 1 < bend) {                      // prefetch next row
            xn0 = *(const float4*)(xp + XROW);
            xn1 = *(const float4*)(xp + XROW + 4);
        }
        xp += XROW;

        const float xf[8] = { xv0.x, xv0.y, xv0.z, xv0.w, xv1.x, xv1.y, xv1.z, xv1.w };

        float z[16];
        #pragma unroll
        for (int k = 0; k < 16; ++k) z[k] = fmaf(xf[0], w1f[0][k], b1f[k]);
        #pragma unroll
        for (int s = 1; s < 8; ++s) {
            #pragma unroll
            for (int k = 0; k < 16; ++k) z[k] = fmaf(xf[s], w1f[s][k], z[k]);
        }

        float acc = 0.f;
        #pragma unroll
        for (int k = 0; k < 16; ++k) {
            float zm  = fminf(z[k], 0.f);
            float e   = __expf(zm) - 1.f;        // z>0 -> e=0
            float elu = fmaxf(z[k], e);          // exact ELU
            acc = fmaf(elu, w2p[k], acc);
        }
        acc += __shfl_xor(acc, 1);               // combine the two h-halves

        if (hg == 0) out[(size_t)b * QN + q] = acc + b2p;
        xv0 = xn0; xv1 = xn1;
    }
}

extern "C" void kernel_launch(void* const* d_in, const int* in_sizes, int n_in,
                              void* d_out, int out_size, void* d_ws, size_t ws_size,
                              hipStream_t stream) {
    const float* x      = (const float*)d_in[0];
    const float* W1     = (const float*)d_in[1];
    const float* b1     = (const float*)d_in[2];
    const float* gamma_ = (const float*)d_in[3];
    const float* beta_  = (const float*)d_in[4];
    const float* mmean  = (const float*)d_in[5];
    const float* mvar   = (const float*)d_in[6];
    const float* W2     = (const float*)d_in[7];
    const float* b2     = (const float*)d_in[8];
    float* out = (float*)d_out;

    const int Btot = in_sizes[0] / XROW;            // 32768
    const int grid_y = 128;                          // 512 blocks, 4 waves each
    const int stripes = grid_y * 4;
    const int b_per_stripe = (Btot + stripes - 1) / stripes;   // 64

    divenc_main<<<dim3(QN / 32, grid_y), 256, 0, stream>>>(
        x, W1, b1, gamma_, beta_, mmean, mvar, W2, b2, out, b_per_stripe, Btot);
}

// Round 3
// 64.888 us; speedup vs baseline: 1.0905x; 1.0905x over previous
//
#include <hip/hip_runtime.h>
#include <hip/hip_bf16.h>

// DivEncLayer: per (b,q): z = W1[q]^T x[b, q*8 .. +8) + b1;  h = BN(elu(z));  out = W2[q]^T h + b2
// B=32768, Q=128, S=8, H=32.  ALL tensors float32.
//
// R2 -> R3: h split 4-ways (8 h per thread) so the W1 fragment is 8x8=64 VGPRs and the
// whole loop state (~117 regs) fits under the 128-VGPR occupancy cliff (4 waves/SIMD).
// R2's h-half split needed ~190 regs -> compiler sank W1 loads into the loop (VGPR=100,
// VALU-time 2.2x ideal). Grid 1024 blocks = 16 waves/CU exactly.
//
// BN folded into second dense: W2p = gamma*rsqrt(var+eps)*W2 ; b2p = b2 + sum((beta-mean*inv)*W2).
// Wave = 16 q x 4 h-quarters; 32B x-load per (thread,row); shfl_xor(1),(2) combine quarters.

#define QN 128
#define SN 8
#define HN 32
#define XROW 1024            // Q*S elements per batch row
#define BN_EPS 1e-3f

__global__ __launch_bounds__(256, 4)
void divenc_main(const float* __restrict__ x,
                 const float* __restrict__ W1,
                 const float* __restrict__ b1,
                 const float* __restrict__ gamma_,
                 const float* __restrict__ beta_,
                 const float* __restrict__ mmean,
                 const float* __restrict__ mvar,
                 const float* __restrict__ W2,
                 const float* __restrict__ b2,
                 float* __restrict__ out,
                 int b_per_stripe, int Btot)
{
    const int lane = threadIdx.x & 63;
    const int wave = threadIdx.x >> 6;
    const int ql   = lane >> 2;        // 0..15 : q within group
    const int hg   = lane & 3;         // 0..3  : h-quarter
    const int q    = blockIdx.x * 16 + ql;
    const int h0   = hg * 8;

    // ---- one-time: BN fold into second dense (f32) ----
    float w2p[8];
    float bsum = 0.f;
    {
        const int base = q * HN + h0;
        #pragma unroll
        for (int k = 0; k < 8; ++k) {
            float g  = gamma_[base + k];
            float bt = beta_[base + k];
            float mn = mmean[base + k];
            float vr = mvar[base + k];
            float w2 = W2[base + k];
            float inv = g * rsqrtf(vr + BN_EPS);
            w2p[k] = inv * w2;
            bsum += (bt - mn * inv) * w2;
        }
    }
    bsum += __shfl_xor(bsum, 1);
    bsum += __shfl_xor(bsum, 2);
    const float b2p = bsum + b2[q];

    // ---- one-time: W1 fragment (8 x 8) and b1 into registers ----
    float w1f[8][8];
    #pragma unroll
    for (int s = 0; s < 8; ++s) {
        const float* wp = W1 + (size_t)(q * SN + s) * HN + h0;
        #pragma unroll
        for (int k = 0; k < 8; ++k) w1f[s][k] = wp[k];
    }
    float b1f[8];
    {
        const float* bp = b1 + q * HN + h0;
        #pragma unroll
        for (int k = 0; k < 8; ++k) b1f[k] = bp[k];
    }

    // ---- main loop over batch rows ----
    const int stripe = blockIdx.y * 4 + wave;
    int b = stripe * b_per_stripe;
    int bend = b + b_per_stripe;
    if (bend > Btot) bend = Btot;
    if (b >= bend) return;

    const float* xp = x + (size_t)b * XROW + q * SN;
    float4 xv0 = *(const float4*)xp;
    float4 xv1 = *(const float4*)(xp + 4);

    for (; b < bend; ++b) {
        // branch-free prefetch of next row (clamped: last iter re-reads current row)
        const float* pf = xp + ((b + 1 < bend) ? XROW : 0);
        float4 xn0 = *(const float4*)pf;
        float4 xn1 = *(const float4*)(pf + 4);
        xp += XROW;

        const float xf[8] = { xv0.x, xv0.y, xv0.z, xv0.w, xv1.x, xv1.y, xv1.z, xv1.w };

        float z[8];
        #pragma unroll
        for (int k = 0; k < 8; ++k) z[k] = fmaf(xf[0], w1f[0][k], b1f[k]);
        #pragma unroll
        for (int s = 1; s < 8; ++s) {
            #pragma unroll
            for (int k = 0; k < 8; ++k) z[k] = fmaf(xf[s], w1f[s][k], z[k]);
        }

        float acc = 0.f;
        #pragma unroll
        for (int k = 0; k < 8; ++k) {
            float zm  = fminf(z[k], 0.f);
            float e   = __expf(zm) - 1.f;        // z>0 -> e=0
            float elu = fmaxf(z[k], e);          // exact ELU
            acc = fmaf(elu, w2p[k], acc);
        }
        acc += __shfl_xor(acc, 1);               // combine the four h-quarters
        acc += __shfl_xor(acc, 2);

        if (hg == 0) out[(size_t)b * QN + q] = acc + b2p;
        xv0 = xn0; xv1 = xn1;
    }
}

extern "C" void kernel_launch(void* const* d_in, const int* in_sizes, int n_in,
                              void* d_out, int out_size, void* d_ws, size_t ws_size,
                              hipStream_t stream) {
    const float* x      = (const float*)d_in[0];
    const float* W1     = (const float*)d_in[1];
    const float* b1     = (const float*)d_in[2];
    const float* gamma_ = (const float*)d_in[3];
    const float* beta_  = (const float*)d_in[4];
    const float* mmean  = (const float*)d_in[5];
    const float* mvar   = (const float*)d_in[6];
    const float* W2     = (const float*)d_in[7];
    const float* b2     = (const float*)d_in[8];
    float* out = (float*)d_out;

    const int Btot = in_sizes[0] / XROW;             // 32768
    const int grid_y = 128;                           // 1024 blocks x 4 waves = 4096 waves
    const int stripes = grid_y * 4;                   // 512 b-stripes
    const int b_per_stripe = (Btot + stripes - 1) / stripes;   // 64

    divenc_main<<<dim3(QN / 16, grid_y), 256, 0, stream>>>(
        x, W1, b1, gamma_, beta_, mmean, mvar, W2, b2, out, b_per_stripe, Btot);
}

// Round 4
// 64.840 us; speedup vs baseline: 1.0913x; 1.0007x over previous
//
#include <hip/hip_runtime.h>
#include <hip/hip_bf16.h>

// DivEncLayer: per (b,q): z = W1[q]^T x[b, q*8 .. +8) + b1;  h = BN(elu(z));  out = W2[q]^T h + b2
// B=32768, Q=128, S=8, H=32.  ALL tensors float32.
//
// R3 -> R4: VGPR_Count=60 proved the compiler kept W1 loads INSIDE the b-loop (w1f alone
// is 64 regs). Fix: pin w1f/b1f/w2p in VGPRs with an empty asm "+v" barrier after the
// one-time load -- the compiler cannot rematerialize an asm output from memory, so the
// fragment stays register-resident (~119 live regs, under the 128 cliff for 4 waves/SIMD).
//
// BN folded into second dense: W2p = gamma*rsqrt(var+eps)*W2 ; b2p = b2 + sum((beta-mean*inv)*W2).
// Wave = 16 q x 4 h-quarters; 32B x-load per (thread,row); shfl_xor(1),(2) combine quarters.

#define QN 128
#define SN 8
#define HN 32
#define XROW 1024            // Q*S elements per batch row
#define BN_EPS 1e-3f

__global__ __launch_bounds__(256, 4)
void divenc_main(const float* __restrict__ x,
                 const float* __restrict__ W1,
                 const float* __restrict__ b1,
                 const float* __restrict__ gamma_,
                 const float* __restrict__ beta_,
                 const float* __restrict__ mmean,
                 const float* __restrict__ mvar,
                 const float* __restrict__ W2,
                 const float* __restrict__ b2,
                 float* __restrict__ out,
                 int b_per_stripe, int Btot)
{
    const int lane = threadIdx.x & 63;
    const int wave = threadIdx.x >> 6;
    const int ql   = lane >> 2;        // 0..15 : q within group
    const int hg   = lane & 3;         // 0..3  : h-quarter
    const int q    = blockIdx.x * 16 + ql;
    const int h0   = hg * 8;

    // ---- one-time: BN fold into second dense (f32) ----
    float w2p[8];
    float bsum = 0.f;
    {
        const int base = q * HN + h0;
        #pragma unroll
        for (int k = 0; k < 8; ++k) {
            float g  = gamma_[base + k];
            float bt = beta_[base + k];
            float mn = mmean[base + k];
            float vr = mvar[base + k];
            float w2 = W2[base + k];
            float inv = g * rsqrtf(vr + BN_EPS);
            w2p[k] = inv * w2;
            bsum += (bt - mn * inv) * w2;
        }
    }
    bsum += __shfl_xor(bsum, 1);
    bsum += __shfl_xor(bsum, 2);
    float b2p = bsum + b2[q];

    // ---- one-time: W1 fragment (8 x 8) and b1 into registers ----
    float w1f[8][8];
    #pragma unroll
    for (int s = 0; s < 8; ++s) {
        const float* wp = W1 + (size_t)(q * SN + s) * HN + h0;
        #pragma unroll
        for (int k = 0; k < 8; ++k) w1f[s][k] = wp[k];
    }
    float b1f[8];
    {
        const float* bp = b1 + q * HN + h0;
        #pragma unroll
        for (int k = 0; k < 8; ++k) b1f[k] = bp[k];
    }

    // ---- PIN the fragments in VGPRs: asm outputs cannot be re-loaded from memory ----
    #pragma unroll
    for (int s = 0; s < 8; ++s) {
        #pragma unroll
        for (int k = 0; k < 8; ++k) asm volatile("" : "+v"(w1f[s][k]));
    }
    #pragma unroll
    for (int k = 0; k < 8; ++k) asm volatile("" : "+v"(b1f[k]));
    #pragma unroll
    for (int k = 0; k < 8; ++k) asm volatile("" : "+v"(w2p[k]));
    asm volatile("" : "+v"(b2p));

    // ---- main loop over batch rows ----
    const int stripe = blockIdx.y * 4 + wave;
    int b = stripe * b_per_stripe;
    int bend = b + b_per_stripe;
    if (bend > Btot) bend = Btot;
    if (b >= bend) return;

    const float* xp = x + (size_t)b * XROW + q * SN;
    float*       op = out + (size_t)b * QN + q;
    float4 xv0 = *(const float4*)xp;
    float4 xv1 = *(const float4*)(xp + 4);

    for (; b < bend; ++b) {
        // branch-free prefetch of next row (clamped: last iter re-reads current row)
        const float* pf = xp + ((b + 1 < bend) ? XROW : 0);
        float4 xn0 = *(const float4*)pf;
        float4 xn1 = *(const float4*)(pf + 4);
        xp += XROW;

        const float xf[8] = { xv0.x, xv0.y, xv0.z, xv0.w, xv1.x, xv1.y, xv1.z, xv1.w };

        float z[8];
        #pragma unroll
        for (int k = 0; k < 8; ++k) z[k] = fmaf(xf[0], w1f[0][k], b1f[k]);
        #pragma unroll
        for (int s = 1; s < 8; ++s) {
            #pragma unroll
            for (int k = 0; k < 8; ++k) z[k] = fmaf(xf[s], w1f[s][k], z[k]);
        }

        float acc = 0.f;
        #pragma unroll
        for (int k = 0; k < 8; ++k) {
            float zm  = fminf(z[k], 0.f);
            float e   = __expf(zm) - 1.f;        // z>0 -> e=0
            float elu = fmaxf(z[k], e);          // exact ELU
            acc = fmaf(elu, w2p[k], acc);
        }
        acc += __shfl_xor(acc, 1);               // combine the four h-quarters
        acc += __shfl_xor(acc, 2);

        if (hg == 0) *op = acc + b2p;
        op += QN;
        xv0 = xn0; xv1 = xn1;
    }
}

extern "C" void kernel_launch(void* const* d_in, const int* in_sizes, int n_in,
                              void* d_out, int out_size, void* d_ws, size_t ws_size,
                              hipStream_t stream) {
    const float* x      = (const float*)d_in[0];
    const float* W1     = (const float*)d_in[1];
    const float* b1     = (const float*)d_in[2];
    const float* gamma_ = (const float*)d_in[3];
    const float* beta_  = (const float*)d_in[4];
    const float* mmean  = (const float*)d_in[5];
    const float* mvar   = (const float*)d_in[6];
    const float* W2     = (const float*)d_in[7];
    const float* b2     = (const float*)d_in[8];
    float* out = (float*)d_out;

    const int Btot = in_sizes[0] / XROW;             // 32768
    const int grid_y = 128;                           // 1024 blocks x 4 waves = 4096 waves
    const int stripes = grid_y * 4;                   // 512 b-stripes
    const int b_per_stripe = (Btot + stripes - 1) / stripes;   // 64

    divenc_main<<<dim3(QN / 16, grid_y), 256, 0, stream>>>(
        x, W1, b1, gamma_, beta_, mmean, mvar, W2, b2, out, b_per_stripe, Btot);
}

// Round 5
// 56.063 us; speedup vs baseline: 1.2622x; 1.1565x over previous
//
#include <hip/hip_runtime.h>
#include <hip/hip_bf16.h>

// DivEncLayer via MFMA. per (b,q): z = W1[q]^T x_slice + b1; out = sum_h w2p*elu(z) + b2p.
// B=32768, Q=128, S=8, H=32, all f32 I/O; compute: bf16 MFMA dense1, f32 VALU epilogue.
//
// R4 -> R5: regalloc refuses to keep a 64-reg invariant W1 array (VGPR=60 twice; asm-pin
// spilled to scratch). Restructure: dense1 = mfma_f32_32x32x16_bf16 per (q, 32-b-tile):
//   A (M=32 h, K=16) = W1^T, k0-7 real, k8 = b1 bias col (B-side k8 = 1.0), k9-15 = 0.
//   B (K=16, N=32 b) = x rows as bf16; lanes 0-31 carry k0-7, lanes 32-63 carry bias consts.
//   D: col=lane&31=b-local, row h=(reg&3)+8*(reg>>2)+4*(lane>>5)  [m74/m101 verified].
// Weight state per q = 4 VGPRs (A) + 16 w2p, re-read each iter from prepacked ws (L2-hot):
// nothing loop-invariant to spill. Out staged in LDS [64][65] then dumped coalesced.

#define QN 128
#define SN 8
#define HN 32
#define XROW 1024
#define BN_EPS 1e-3f

typedef short bf16x8 __attribute__((ext_vector_type(8)));
typedef float f32x16 __attribute__((ext_vector_type(16)));
typedef unsigned int u32;

#define WS_A_BYTES   (QN * 64 * 16)              // 128 KiB: per-q per-lane 16B A-fragments
#define WS_W2P_OFF   WS_A_BYTES
#define WS_W2P_BYTES (QN * 32 * 4)               // 16 KiB: [q][half][reg] f32
#define WS_B2P_OFF   (WS_W2P_OFF + WS_W2P_BYTES) // 512 B: [q] f32

static __device__ __forceinline__ u32 pkbf(float lo, float hi) {
    union { __hip_bfloat162 h2; u32 u; } c;
    c.h2 = __float22bfloat162_rn(float2{lo, hi});
    return c.u;
}

// ---- prep: pack A-fragments (bf16, MFMA layout), BN-folded w2p (reg order), b2p ----
__global__ void divenc_prep(const float* __restrict__ W1,
                            const float* __restrict__ b1,
                            const float* __restrict__ gamma_,
                            const float* __restrict__ beta_,
                            const float* __restrict__ mmean,
                            const float* __restrict__ mvar,
                            const float* __restrict__ W2,
                            const float* __restrict__ b2,
                            unsigned char* __restrict__ ws)
{
    const int q = blockIdx.x;        // 0..127
    const int m = threadIdx.x;       // 0..63 = MFMA lane

    u32 d0 = 0, d1 = 0, d2 = 0, d3 = 0;
    if (m < 32) {                    // k-group 0: k = 0..7 of W1[q][k][h=m]
        const int h = m;
        d0 = pkbf(W1[(q*SN + 0)*HN + h], W1[(q*SN + 1)*HN + h]);
        d1 = pkbf(W1[(q*SN + 2)*HN + h], W1[(q*SN + 3)*HN + h]);
        d2 = pkbf(W1[(q*SN + 4)*HN + h], W1[(q*SN + 5)*HN + h]);
        d3 = pkbf(W1[(q*SN + 6)*HN + h], W1[(q*SN + 7)*HN + h]);
    } else {                         // k-group 1: k=8 -> b1 (bias col), k9..15 -> 0
        const int h = m - 32;
        d0 = pkbf(b1[q*HN + h], 0.f);
    }
    ((uint4*)ws)[q*64 + m] = uint4{d0, d1, d2, d3};

    float* wsW2p = (float*)(ws + WS_W2P_OFF);
    float* wsB2p = (float*)(ws + WS_B2P_OFF);
    if (m < 32) {                    // w2p in D-register order: h = (r&3)+8*(r>>2)+4*half
        const int half = m >> 4, r = m & 15;
        const int h = (r & 3) + 8*(r >> 2) + 4*half;
        float inv = gamma_[q*HN+h] * rsqrtf(mvar[q*HN+h] + BN_EPS);
        wsW2p[q*32 + half*16 + r] = inv * W2[q*HN + h];
    }
    if (m == 0) {
        float acc = b2[q];
        for (int h = 0; h < HN; ++h) {
            float inv = gamma_[q*HN+h] * rsqrtf(mvar[q*HN+h] + BN_EPS);
            acc += (beta_[q*HN+h] - mmean[q*HN+h]*inv) * W2[q*HN+h];
        }
        wsB2p[q] = acc;
    }
}

// ---- main: block = 4 waves, 64 b-rows x 64 q.  wave w owns q-range [qh*64+w*16, +16) ----
__global__ __launch_bounds__(256, 4)
void divenc_mfma(const float* __restrict__ x,
                 const unsigned char* __restrict__ ws,
                 float* __restrict__ out)
{
    const int lane = threadIdx.x & 63;
    const int wv   = threadIdx.x >> 6;
    const int b0   = blockIdx.x * 64;
    const int qh   = blockIdx.y;          // 0..1
    const int half = lane >> 5;
    const int bl   = lane & 31;

    const uint4*  wsA  = (const uint4*)ws;
    const float*  wsW  = (const float*)(ws + WS_W2P_OFF);
    const float*  wsB2 = (const float*)(ws + WS_B2P_OFF);

    __shared__ float lds_out[64][65];

    const float* xrow = x + (size_t)(b0 + lane) * XROW;
    const u32 biasB = 0x00003F80u;        // bf16(1.0) at k=8, rest 0

    for (int it = 0; it < 4; ++it) {
        const int qb = qh*64 + wv*16 + it*4;

        // x for this lane's row, q in [qb, qb+4): 128B line-aligned
        float4 xr[8];
        #pragma unroll
        for (int j = 0; j < 8; ++j)
            xr[j] = ((const float4*)(xrow + qb*SN))[j];

        u32 xb[16];                        // bf16-packed, dword d of q-local ql at [ql*4+d]
        #pragma unroll
        for (int j = 0; j < 8; ++j) {
            xb[2*j]   = pkbf(xr[j].x, xr[j].y);
            xb[2*j+1] = pkbf(xr[j].z, xr[j].w);
        }

        #pragma unroll
        for (int ql = 0; ql < 4; ++ql) {
            const int q      = qb + ql;
            const int qlocal = wv*16 + it*4 + ql;

            union { uint4 u; bf16x8 v; } A, B0, B1;
            A.u = wsA[q*64 + lane];

            const float* wp = wsW + q*32 + half*16;   // same addr across half-wave
            float w2r[16];
            #pragma unroll
            for (int r = 0; r < 16; ++r) w2r[r] = wp[r];
            const float b2p = wsB2[q];

            u32 bx0[4], bx1[4];
            #pragma unroll
            for (int d = 0; d < 4; ++d) {
                u32 own  = xb[ql*4 + d];
                u32 sw   = __shfl_xor(own, 32);       // other b-half's x
                u32 bias = (d == 0) ? biasB : 0u;
                bx0[d] = half ? bias : own;
                bx1[d] = half ? bias : sw;
            }
            B0.u = uint4{bx0[0], bx0[1], bx0[2], bx0[3]};
            B1.u = uint4{bx1[0], bx1[1], bx1[2], bx1[3]};

            f32x16 zero;
            #pragma unroll
            for (int r = 0; r < 16; ++r) zero[r] = 0.f;

            f32x16 dA = __builtin_amdgcn_mfma_f32_32x32x16_bf16(A.v, B0.v, zero, 0, 0, 0);
            float p0 = 0.f;
            #pragma unroll
            for (int r = 0; r < 16; ++r) {
                float z = dA[r];
                float e = __expf(fminf(z, 0.f)) - 1.f;
                p0 = fmaf(fmaxf(z, e), w2r[r], p0);
            }
            p0 += __shfl_xor(p0, 32);

            f32x16 dB = __builtin_amdgcn_mfma_f32_32x32x16_bf16(A.v, B1.v, zero, 0, 0, 0);
            float p1 = 0.f;
            #pragma unroll
            for (int r = 0; r < 16; ++r) {
                float z = dB[r];
                float e = __expf(fminf(z, 0.f)) - 1.f;
                p1 = fmaf(fmaxf(z, e), w2r[r], p1);
            }
            p1 += __shfl_xor(p1, 32);

            if (lane < 32) {
                lds_out[bl     ][qlocal] = p0 + b2p;
                lds_out[bl + 32][qlocal] = p1 + b2p;
            }
        }
    }

    __syncthreads();

    // dump: wave wv writes rows [wv*16, +16); 4 rows x 16 cols per pass, 4 col-chunks
    #pragma unroll
    for (int p = 0; p < 4; ++p) {
        const int row = wv*16 + p*4 + (lane >> 4);
        const int c0  = lane & 15;
        float* orow = out + (size_t)(b0 + row) * QN + qh*64;
        #pragma unroll
        for (int cc = 0; cc < 4; ++cc)
            orow[c0 + cc*16] = lds_out[row][c0 + cc*16];
    }
}

extern "C" void kernel_launch(void* const* d_in, const int* in_sizes, int n_in,
                              void* d_out, int out_size, void* d_ws, size_t ws_size,
                              hipStream_t stream) {
    const float* x      = (const float*)d_in[0];
    const float* W1     = (const float*)d_in[1];
    const float* b1     = (const float*)d_in[2];
    const float* gamma_ = (const float*)d_in[3];
    const float* beta_  = (const float*)d_in[4];
    const float* mmean  = (const float*)d_in[5];
    const float* mvar   = (const float*)d_in[6];
    const float* W2     = (const float*)d_in[7];
    const float* b2     = (const float*)d_in[8];
    float* out = (float*)d_out;
    unsigned char* ws = (unsigned char*)d_ws;

    const int Btot = in_sizes[0] / XROW;          // 32768

    divenc_prep<<<QN, 64, 0, stream>>>(W1, b1, gamma_, beta_, mmean, mvar, W2, b2, ws);
    divenc_mfma<<<dim3(Btot / 64, 2), 256, 0, stream>>>(x, ws, out);
}

// Round 6
// 49.906 us; speedup vs baseline: 1.4179x; 1.1234x over previous
//
#include <hip/hip_runtime.h>
#include <hip/hip_bf16.h>

// DivEncLayer via MFMA, R6. per (b,q): z = W1^T x + b1; out = sum_h w2p*elu(z) + b2p.
// B=32768, Q=128, S=8, H=32, f32 I/O; bf16 MFMA dense1, f32 epilogue.
//
// R5 -> R6 (counter-driven): VALUBusy 40%/Occ 33%/VGPR 44 = latency+issue bound.
//  1. C-operand = b1 (f32, D-reg order) -> no zero-init movs, no bias column.
//  2. A1 = W1 @ k0-7 (lanes<32), A2 = same bytes read at lane^32 (k8-15): both MFMAs
//     share ONE B (each lane's own x row) -> zero ds_bpermute, zero cndmask.
//     D0 = b-rows 0-31, D1 = b-rows 32-63 of the 64-row sub-tile.
//  3. Block = 8 waves x 256 b-rows x 32 q. Weights (A1,A2,c,w2p,b2p = 41 regs) loaded
//     once per q, amortized over 4 unrolled sub-tiles; x prefetched one sub ahead.
//     Out staged in double-buffered slab[2][256][9] -> 4 barriers/block, 16B dumps.

#define QN 128
#define SN 8
#define HN 32
#define XROW 1024
#define BN_EPS 1e-3f

typedef short bf16x8 __attribute__((ext_vector_type(8)));
typedef float f32x16 __attribute__((ext_vector_type(16)));
typedef unsigned int u32;

#define WS_A_BYTES (QN * 64 * 16)                 // 128 KiB: A1pack[q][lane] 16B (hi lanes zero)
#define WS_C_OFF   WS_A_BYTES
#define WS_C_BYTES (QN * 32 * 4)                  // c_init[q][half*16+r] = b1 (f32, reg order)
#define WS_W_OFF   (WS_C_OFF + WS_C_BYTES)
#define WS_W_BYTES (QN * 32 * 4)                  // w2p[q][half*16+r]   (f32, reg order)
#define WS_B2_OFF  (WS_W_OFF + WS_W_BYTES)        // b2p[q]

static __device__ __forceinline__ u32 pkbf(float lo, float hi) {
    union { __hip_bfloat162 h2; u32 u; } c;
    c.h2 = __float22bfloat162_rn(float2{lo, hi});
    return c.u;
}

__global__ void divenc_prep(const float* __restrict__ W1, const float* __restrict__ b1,
                            const float* __restrict__ gamma_, const float* __restrict__ beta_,
                            const float* __restrict__ mmean, const float* __restrict__ mvar,
                            const float* __restrict__ W2, const float* __restrict__ b2,
                            unsigned char* __restrict__ ws)
{
    const int q = blockIdx.x;        // 0..127
    const int m = threadIdx.x;       // 0..63

    u32 d0 = 0, d1 = 0, d2 = 0, d3 = 0;
    if (m < 32) {                    // A[m][k] = W1[q][k][m], k pairs per dword
        d0 = pkbf(W1[(q*SN + 0)*HN + m], W1[(q*SN + 1)*HN + m]);
        d1 = pkbf(W1[(q*SN + 2)*HN + m], W1[(q*SN + 3)*HN + m]);
        d2 = pkbf(W1[(q*SN + 4)*HN + m], W1[(q*SN + 5)*HN + m]);
        d3 = pkbf(W1[(q*SN + 6)*HN + m], W1[(q*SN + 7)*HN + m]);
    }
    ((uint4*)ws)[q*64 + m] = uint4{d0, d1, d2, d3};

    float* wsC  = (float*)(ws + WS_C_OFF);
    float* wsW  = (float*)(ws + WS_W_OFF);
    float* wsB2 = (float*)(ws + WS_B2_OFF);
    if (m < 32) {                    // D-reg order: h = (r&3) + 8*(r>>2) + 4*half
        const int half = m >> 4, r = m & 15;
        const int h = (r & 3) + 8*(r >> 2) + 4*half;
        wsC[q*32 + m] = b1[q*HN + h];
        float inv = gamma_[q*HN+h] * rsqrtf(mvar[q*HN+h] + BN_EPS);
        wsW[q*32 + m] = inv * W2[q*HN + h];
    }
    if (m == 0) {
        float acc = b2[q];
        for (int h = 0; h < HN; ++h) {
            float inv = gamma_[q*HN+h] * rsqrtf(mvar[q*HN+h] + BN_EPS);
            acc += (beta_[q*HN+h] - mmean[q*HN+h]*inv) * W2[q*HN+h];
        }
        wsB2[q] = acc;
    }
}

__global__ __launch_bounds__(512, 4)
void divenc_mfma(const float* __restrict__ x, const unsigned char* __restrict__ ws,
                 float* __restrict__ out)
{
    const int lane = threadIdx.x & 63;
    const int wv   = threadIdx.x >> 6;   // 0..7
    const int half = lane >> 5;
    const int bl   = lane & 31;
    const int b0   = blockIdx.x * 256;
    const int q0   = blockIdx.y * 32;

    const uint4* wsA  = (const uint4*)ws;
    const float* wsC  = (const float*)(ws + WS_C_OFF);
    const float* wsW  = (const float*)(ws + WS_W_OFF);
    const float* wsB2 = (const float*)(ws + WS_B2_OFF);

    __shared__ float slab[2][256][9];    // 18.4 KiB, double-buffered across qg

    #pragma unroll
    for (int qg = 0; qg < 4; ++qg) {
        const int q = q0 + qg*8 + wv;

        union { uint4 u; bf16x8 v; } A1, A2;
        A1.u = wsA[q*64 + lane];          // W1 in lanes<32 (k0-7), zeros above
        A2.u = wsA[q*64 + (lane ^ 32)];   // same bytes -> W1 in lanes>=32 (k8-15)

        f32x16 cini;
        const float* cp_ = wsC + q*32 + half*16;
        #pragma unroll
        for (int r = 0; r < 16; ++r) cini[r] = cp_[r];
        float w2r[16];
        const float* wp_ = wsW + q*32 + half*16;
        #pragma unroll
        for (int r = 0; r < 16; ++r) w2r[r] = wp_[r];
        const float b2p = wsB2[q];

        const float* xq = x + (size_t)b0 * XROW + q * SN;
        float4 xa = *(const float4*)(xq + (size_t)lane * XROW);
        float4 xc = *(const float4*)(xq + (size_t)lane * XROW + 4);

        #pragma unroll
        for (int sub = 0; sub < 4; ++sub) {
            // prefetch next sub's x (clamped re-read on last iter: L1-hit, harmless)
            const int nsub = (sub < 3) ? sub + 1 : sub;
            const float* np = xq + (size_t)(nsub*64 + lane) * XROW;
            float4 na = *(const float4*)np;
            float4 nc = *(const float4*)(np + 4);

            union { uint4 u; bf16x8 v; } B;
            B.u = uint4{ pkbf(xa.x, xa.y), pkbf(xa.z, xa.w),
                         pkbf(xc.x, xc.y), pkbf(xc.z, xc.w) };

            f32x16 D0 = __builtin_amdgcn_mfma_f32_32x32x16_bf16(A1.v, B.v, cini, 0, 0, 0);
            f32x16 D1 = __builtin_amdgcn_mfma_f32_32x32x16_bf16(A2.v, B.v, cini, 0, 0, 0);

            float p0 = 0.f, p1 = 0.f;
            #pragma unroll
            for (int r = 0; r < 16; ++r) {
                float z0 = D0[r];
                float e0 = __expf(fminf(z0, 0.f)) - 1.f;
                p0 = fmaf(fmaxf(z0, e0), w2r[r], p0);
                float z1 = D1[r];
                float e1 = __expf(fminf(z1, 0.f)) - 1.f;
                p1 = fmaf(fmaxf(z1, e1), w2r[r], p1);
            }
            p0 += __shfl_xor(p0, 32);     // combine the two h-halves (same b-col)
            p1 += __shfl_xor(p1, 32);

            const float v = (half ? p1 : p0) + b2p;
            slab[qg & 1][sub*64 + half*32 + bl][wv] = v;

            xa = na; xc = nc;
        }

        __syncthreads();                  // slab[qg&1] complete; qg+1 uses other slab
        {
            const int row = threadIdx.x >> 1;         // 0..255
            const int cp  = (threadIdx.x & 1) * 4;    // 0 or 4
            float4 vv;
            vv.x = slab[qg & 1][row][cp + 0];
            vv.y = slab[qg & 1][row][cp + 1];
            vv.z = slab[qg & 1][row][cp + 2];
            vv.w = slab[qg & 1][row][cp + 3];
            *(float4*)(out + (size_t)(b0 + row) * QN + q0 + qg*8 + cp) = vv;
        }
    }
}

extern "C" void kernel_launch(void* const* d_in, const int* in_sizes, int n_in,
                              void* d_out, int out_size, void* d_ws, size_t ws_size,
                              hipStream_t stream) {
    const float* x      = (const float*)d_in[0];
    const float* W1     = (const float*)d_in[1];
    const float* b1     = (const float*)d_in[2];
    const float* gamma_ = (const float*)d_in[3];
    const float* beta_  = (const float*)d_in[4];
    const float* mmean  = (const float*)d_in[5];
    const float* mvar   = (const float*)d_in[6];
    const float* W2     = (const float*)d_in[7];
    const float* b2     = (const float*)d_in[8];
    float* out = (float*)d_out;
    unsigned char* ws = (unsigned char*)d_ws;

    const int Btot = in_sizes[0] / XROW;              // 32768

    divenc_prep<<<QN, 64, 0, stream>>>(W1, b1, gamma_, beta_, mmean, mvar, W2, b2, ws);
    divenc_mfma<<<dim3(Btot / 256, QN / 32), 512, 0, stream>>>(x, ws, out);
}